// Round 2
// baseline (161.375 us; speedup 1.0000x reference)
//
#include <hip/hip_runtime.h>

// TensorProduct: N=100000, C=128
// x1: (N, 512) = [s1 (128) | v1 (128x3 interleaved)]
// x2: (N, 4)   = [s2 | v2 (3)]
// w : (N, 640) = 5 paths x 128 channels
// out: (N, 896) = [out_s (128) | out_vo (128x3) | out_ve (128x3)]
//
// One thread handles 4 consecutive channels -> every global access is dwordx4.

#define C 128

__global__ void __launch_bounds__(256) TensorProduct_86397562126686_kernel(
    const float* __restrict__ x1,
    const float* __restrict__ x2,
    const float* __restrict__ w,
    float* __restrict__ out,
    int N)
{
    int tid = blockIdx.x * blockDim.x + threadIdx.x;
    int total = N * (C / 4);          // 32 threads per row
    if (tid >= total) return;

    int n  = tid >> 5;                // row
    int c0 = (tid & 31) << 2;         // first of 4 channels

    const float* __restrict__ x1r = x1 + (size_t)n * (4 * C);
    const float* __restrict__ wr  = w  + (size_t)n * (5 * C);

    // x2 row: broadcast across the row's 32 threads
    float4 x2v = *reinterpret_cast<const float4*>(x2 + (size_t)n * 4);
    const float s2  = x2v.x;
    const float v2x = x2v.y;
    const float v2y = x2v.z;
    const float v2z = x2v.w;

    // s1: 4 channels
    float4 s1v = *reinterpret_cast<const float4*>(x1r + c0);

    // v1: 12 consecutive floats = 3 float4s (16B-aligned: byte off = 512 + 48*t)
    const float4* __restrict__ v1p4 = reinterpret_cast<const float4*>(x1r + C + 3 * c0);
    float4 b0 = v1p4[0];
    float4 b1 = v1p4[1];
    float4 b2 = v1p4[2];
    float v1f[12] = { b0.x, b0.y, b0.z, b0.w,
                      b1.x, b1.y, b1.z, b1.w,
                      b2.x, b2.y, b2.z, b2.w };

    // weights: 5 paths x 4 channels
    float4 w0v = *reinterpret_cast<const float4*>(wr + 0 * C + c0);
    float4 w1v = *reinterpret_cast<const float4*>(wr + 1 * C + c0);
    float4 w2v = *reinterpret_cast<const float4*>(wr + 2 * C + c0);
    float4 w3v = *reinterpret_cast<const float4*>(wr + 3 * C + c0);
    float4 w4v = *reinterpret_cast<const float4*>(wr + 4 * C + c0);

    const float pw2 = 0.70710678118654752440f;   // 1/sqrt(2)
    const float is3 = 0.57735026918962576451f;   // 1/sqrt(3)

    float s1a[4] = { s1v.x, s1v.y, s1v.z, s1v.w };
    float w0a[4] = { w0v.x, w0v.y, w0v.z, w0v.w };
    float w1a[4] = { w1v.x, w1v.y, w1v.z, w1v.w };
    float w2a[4] = { w2v.x, w2v.y, w2v.z, w2v.w };
    float w3a[4] = { w3v.x, w3v.y, w3v.z, w3v.w };
    float w4a[4] = { w4v.x, w4v.y, w4v.z, w4v.w };

    float outs[4];
    float vo[12];
    float ve[12];

#pragma unroll
    for (int j = 0; j < 4; ++j) {
        float s1 = s1a[j];
        float a0 = v1f[3 * j + 0];
        float a1 = v1f[3 * j + 1];
        float a2 = v1f[3 * j + 2];

        float dot = a0 * v2x + a1 * v2y + a2 * v2z;
        outs[j] = pw2 * (w0a[j] * s1 * s2 + w1a[j] * is3 * dot);

        vo[3 * j + 0] = pw2 * (w2a[j] * s1 * v2x + w3a[j] * a0 * s2);
        vo[3 * j + 1] = pw2 * (w2a[j] * s1 * v2y + w3a[j] * a1 * s2);
        vo[3 * j + 2] = pw2 * (w2a[j] * s1 * v2z + w3a[j] * a2 * s2);

        float cx = a1 * v2z - a2 * v2y;
        float cy = a2 * v2x - a0 * v2z;
        float cz = a0 * v2y - a1 * v2x;
        float pww4 = pw2 * w4a[j];
        ve[3 * j + 0] = pww4 * cx;
        ve[3 * j + 1] = pww4 * cy;
        ve[3 * j + 2] = pww4 * cz;
    }

    float* __restrict__ outr = out + (size_t)n * 896;

    *reinterpret_cast<float4*>(outr + c0) =
        make_float4(outs[0], outs[1], outs[2], outs[3]);

    float4* __restrict__ vop = reinterpret_cast<float4*>(outr + C + 3 * c0);
    vop[0] = make_float4(vo[0], vo[1], vo[2],  vo[3]);
    vop[1] = make_float4(vo[4], vo[5], vo[6],  vo[7]);
    vop[2] = make_float4(vo[8], vo[9], vo[10], vo[11]);

    float4* __restrict__ vep = reinterpret_cast<float4*>(outr + 4 * C + 3 * c0);
    vep[0] = make_float4(ve[0], ve[1], ve[2],  ve[3]);
    vep[1] = make_float4(ve[4], ve[5], ve[6],  ve[7]);
    vep[2] = make_float4(ve[8], ve[9], ve[10], ve[11]);
}

extern "C" void kernel_launch(void* const* d_in, const int* in_sizes, int n_in,
                              void* d_out, int out_size, void* d_ws, size_t ws_size,
                              hipStream_t stream) {
    const float* x1 = (const float*)d_in[0];
    const float* x2 = (const float*)d_in[1];
    const float* w  = (const float*)d_in[2];
    float* out = (float*)d_out;

    int N = in_sizes[0] / (4 * C);    // 100000
    int total = N * (C / 4);          // 3.2M threads
    int block = 256;
    int grid = (total + block - 1) / block;

    TensorProduct_86397562126686_kernel<<<grid, block, 0, stream>>>(x1, x2, w, out, N);
}

// Round 3
// 147.088 us; speedup vs baseline: 1.0971x; 1.0971x over previous
//
#include <hip/hip_runtime.h>

// TensorProduct: N=100000, C=128
// x1: (N, 512) = [s1 (128) | v1 (128x3 interleaved)]
// x2: (N, 4)   = [s2 | v2 (3)]
// w : (N, 640) = 5 paths x 128 channels
// out: (N, 896) = [out_s (128) | out_vo (128x3) | out_ve (128x3)]
//
// Strategy: LDS-staged, fully-coalesced global I/O.
//   Block = 256 threads = 4 rows. All global loads/stores are dwordx4 with
//   consecutive lanes hitting consecutive 16B — no strided global traffic.
//   Compute phase: 64 threads/row, 2 channels/thread, reads/writes LDS.

#define C 128
#define R 4   // rows per block

__global__ void __launch_bounds__(256) TensorProduct_86397562126686_kernel(
    const float* __restrict__ x1,
    const float* __restrict__ x2,
    const float* __restrict__ w,
    float* __restrict__ out,
    int N)
{
    __shared__ float4 s_x1[R * 128];   // R*512 floats = 8 KB
    __shared__ float4 s_w [R * 160];   // R*640 floats = 10 KB
    __shared__ float4 s_x2[R];         // R*4 floats
    __shared__ float4 s_out[R * 224];  // R*896 floats = 14 KB

    const int t = threadIdx.x;
    const size_t n0 = (size_t)blockIdx.x * R;

    // ---- stage inputs: perfectly coalesced float4 ----
    const float4* __restrict__ gx1 = reinterpret_cast<const float4*>(x1 + n0 * 512);
    const float4* __restrict__ gw  = reinterpret_cast<const float4*>(w  + n0 * 640);
    const float4* __restrict__ gx2 = reinterpret_cast<const float4*>(x2 + n0 * 4);

    s_x1[t]        = gx1[t];          // 512 float4 total
    s_x1[t + 256]  = gx1[t + 256];
    s_w[t]         = gw[t];           // 640 float4 total
    s_w[t + 256]   = gw[t + 256];
    if (t < 128) s_w[t + 512] = gw[t + 512];
    if (t < R)   s_x2[t] = gx2[t];

    __syncthreads();

    // ---- compute: row r = t/64, channels {2i, 2i+1}, i = t%64 ----
    {
        const int r  = t >> 6;
        const int i  = t & 63;
        const int c0 = i << 1;

        const float* __restrict__ px1 = reinterpret_cast<const float*>(s_x1) + r * 512;
        const float* __restrict__ pw  = reinterpret_cast<const float*>(s_w)  + r * 640;
        float*       __restrict__ po  = reinterpret_cast<float*>(s_out)      + r * 896;

        float4 x2v = s_x2[r];
        const float s2  = x2v.x;
        const float v2x = x2v.y;
        const float v2y = x2v.z;
        const float v2z = x2v.w;

        float2 s1v = *reinterpret_cast<const float2*>(px1 + c0);
        const float* v1p = px1 + C + 3 * c0;          // 6 floats, 8B-aligned (c0 even)
        float2 va = *reinterpret_cast<const float2*>(v1p);
        float2 vb = *reinterpret_cast<const float2*>(v1p + 2);
        float2 vc = *reinterpret_cast<const float2*>(v1p + 4);

        float2 w0v = *reinterpret_cast<const float2*>(pw + 0 * C + c0);
        float2 w1v = *reinterpret_cast<const float2*>(pw + 1 * C + c0);
        float2 w2v = *reinterpret_cast<const float2*>(pw + 2 * C + c0);
        float2 w3v = *reinterpret_cast<const float2*>(pw + 3 * C + c0);
        float2 w4v = *reinterpret_cast<const float2*>(pw + 4 * C + c0);

        const float pw2 = 0.70710678118654752440f;   // 1/sqrt(2)
        const float is3 = 0.57735026918962576451f;   // 1/sqrt(3)

        // channel 0: v1 = (va.x, va.y, vb.x); channel 1: v1 = (vb.y, vc.x, vc.y)
        float s1a[2] = { s1v.x, s1v.y };
        float a0a[2] = { va.x, vb.y };
        float a1a[2] = { va.y, vc.x };
        float a2a[2] = { vb.x, vc.y };
        float w0a[2] = { w0v.x, w0v.y };
        float w1a[2] = { w1v.x, w1v.y };
        float w2a[2] = { w2v.x, w2v.y };
        float w3a[2] = { w3v.x, w3v.y };
        float w4a[2] = { w4v.x, w4v.y };

        float outs[2], vo[6], ve[6];

#pragma unroll
        for (int j = 0; j < 2; ++j) {
            float s1 = s1a[j];
            float a0 = a0a[j], a1 = a1a[j], a2 = a2a[j];

            float dot = a0 * v2x + a1 * v2y + a2 * v2z;
            outs[j] = pw2 * (w0a[j] * s1 * s2 + w1a[j] * is3 * dot);

            vo[3 * j + 0] = pw2 * (w2a[j] * s1 * v2x + w3a[j] * a0 * s2);
            vo[3 * j + 1] = pw2 * (w2a[j] * s1 * v2y + w3a[j] * a1 * s2);
            vo[3 * j + 2] = pw2 * (w2a[j] * s1 * v2z + w3a[j] * a2 * s2);

            float cx = a1 * v2z - a2 * v2y;
            float cy = a2 * v2x - a0 * v2z;
            float cz = a0 * v2y - a1 * v2x;
            float pww4 = pw2 * w4a[j];
            ve[3 * j + 0] = pww4 * cx;
            ve[3 * j + 1] = pww4 * cy;
            ve[3 * j + 2] = pww4 * cz;
        }

        *reinterpret_cast<float2*>(po + c0) = make_float2(outs[0], outs[1]);

        float* vop = po + C + 3 * c0;
        *reinterpret_cast<float2*>(vop)     = make_float2(vo[0], vo[1]);
        *reinterpret_cast<float2*>(vop + 2) = make_float2(vo[2], vo[3]);
        *reinterpret_cast<float2*>(vop + 4) = make_float2(vo[4], vo[5]);

        float* vep = po + 4 * C + 3 * c0;
        *reinterpret_cast<float2*>(vep)     = make_float2(ve[0], ve[1]);
        *reinterpret_cast<float2*>(vep + 2) = make_float2(ve[2], ve[3]);
        *reinterpret_cast<float2*>(vep + 4) = make_float2(ve[4], ve[5]);
    }

    __syncthreads();

    // ---- store outputs: perfectly coalesced float4 ----
    float4* __restrict__ gout = reinterpret_cast<float4*>(out + n0 * 896);
    gout[t]        = s_out[t];          // 896 float4 total
    gout[t + 256]  = s_out[t + 256];
    gout[t + 512]  = s_out[t + 512];
    if (t < 128) gout[t + 768] = s_out[t + 768];
}

extern "C" void kernel_launch(void* const* d_in, const int* in_sizes, int n_in,
                              void* d_out, int out_size, void* d_ws, size_t ws_size,
                              hipStream_t stream) {
    const float* x1 = (const float*)d_in[0];
    const float* x2 = (const float*)d_in[1];
    const float* w  = (const float*)d_in[2];
    float* out = (float*)d_out;

    int N = in_sizes[0] / (4 * C);    // 100000 (divisible by R=4)
    int grid = N / R;                 // 25000 blocks
    TensorProduct_86397562126686_kernel<<<grid, 256, 0, stream>>>(x1, x2, w, out, N);
}

// Round 4
// 137.764 us; speedup vs baseline: 1.1714x; 1.0677x over previous
//
#include <hip/hip_runtime.h>

// TensorProduct: N=100000, C=128
// x1: (N, 512) = [s1 (128) | v1 (128x3 interleaved)]
// x2: (N, 4)   = [s2 | v2 (3)]
// w : (N, 640) = 5 paths x 128 channels
// out: (N, 896) = [out_s (128) | out_vo (128x3) | out_ve (128x3)]
//
// Round 4: round-3 structure (LDS-staged, fully-coalesced dwordx4 global I/O)
//  + non-temporal hints on all streaming global accesses (read-once/write-once,
//    avoid L2/LLC retention)
//  + s_out aliased over the input LDS region (18.5 KB total -> 8 blocks/CU,
//    100% occupancy; inputs fully consumed before the aliased write, guarded
//    by an extra barrier)

#define C 128
#define R 4   // rows per block

typedef float f4v __attribute__((ext_vector_type(4)));

__global__ void __launch_bounds__(256) TensorProduct_86397562126686_kernel(
    const float* __restrict__ x1,
    const float* __restrict__ x2,
    const float* __restrict__ w,
    float* __restrict__ out,
    int N)
{
    // 1156 float4 = 18.5 KB
    // inputs:  [0..511]=x1 (R*512 f), [512..1151]=w (R*640 f), [1152..1155]=x2
    // outputs: [0..895]=out (R*896 f)  -- aliased over x1/w after compute
    __shared__ f4v smem[1156];
    f4v* __restrict__ s_x1 = smem;
    f4v* __restrict__ s_w  = smem + 512;
    f4v* __restrict__ s_x2 = smem + 1152;
    f4v* __restrict__ s_out = smem;   // alias

    const int t = threadIdx.x;
    const size_t n0 = (size_t)blockIdx.x * R;

    // ---- stage inputs: coalesced non-temporal dwordx4 ----
    const f4v* __restrict__ gx1 = reinterpret_cast<const f4v*>(x1 + n0 * 512);
    const f4v* __restrict__ gw  = reinterpret_cast<const f4v*>(w  + n0 * 640);
    const f4v* __restrict__ gx2 = reinterpret_cast<const f4v*>(x2 + n0 * 4);

    s_x1[t]       = __builtin_nontemporal_load(gx1 + t);
    s_x1[t + 256] = __builtin_nontemporal_load(gx1 + t + 256);
    s_w[t]        = __builtin_nontemporal_load(gw + t);
    s_w[t + 256]  = __builtin_nontemporal_load(gw + t + 256);
    if (t < 128) s_w[t + 512] = __builtin_nontemporal_load(gw + t + 512);
    if (t < R)   s_x2[t]      = __builtin_nontemporal_load(gx2 + t);

    __syncthreads();

    // ---- compute: row r = t/64, channels {2i, 2i+1}, i = t%64 ----
    float outs[2], vo[6], ve[6];
    const int r  = t >> 6;
    const int i  = t & 63;
    const int c0 = i << 1;
    {
        const float* __restrict__ px1 = reinterpret_cast<const float*>(s_x1) + r * 512;
        const float* __restrict__ pw  = reinterpret_cast<const float*>(s_w)  + r * 640;

        f4v x2v = s_x2[r];
        const float s2  = x2v[0];
        const float v2x = x2v[1];
        const float v2y = x2v[2];
        const float v2z = x2v[3];

        float2 s1v = *reinterpret_cast<const float2*>(px1 + c0);
        const float* v1p = px1 + C + 3 * c0;          // 6 floats, 8B-aligned (c0 even)
        float2 va = *reinterpret_cast<const float2*>(v1p);
        float2 vb = *reinterpret_cast<const float2*>(v1p + 2);
        float2 vc = *reinterpret_cast<const float2*>(v1p + 4);

        float2 w0v = *reinterpret_cast<const float2*>(pw + 0 * C + c0);
        float2 w1v = *reinterpret_cast<const float2*>(pw + 1 * C + c0);
        float2 w2v = *reinterpret_cast<const float2*>(pw + 2 * C + c0);
        float2 w3v = *reinterpret_cast<const float2*>(pw + 3 * C + c0);
        float2 w4v = *reinterpret_cast<const float2*>(pw + 4 * C + c0);

        const float pw2 = 0.70710678118654752440f;   // 1/sqrt(2)
        const float is3 = 0.57735026918962576451f;   // 1/sqrt(3)

        // channel 0: v1 = (va.x, va.y, vb.x); channel 1: v1 = (vb.y, vc.x, vc.y)
        float s1a[2] = { s1v.x, s1v.y };
        float a0a[2] = { va.x, vb.y };
        float a1a[2] = { va.y, vc.x };
        float a2a[2] = { vb.x, vc.y };
        float w0a[2] = { w0v.x, w0v.y };
        float w1a[2] = { w1v.x, w1v.y };
        float w2a[2] = { w2v.x, w2v.y };
        float w3a[2] = { w3v.x, w3v.y };
        float w4a[2] = { w4v.x, w4v.y };

#pragma unroll
        for (int j = 0; j < 2; ++j) {
            float s1 = s1a[j];
            float a0 = a0a[j], a1 = a1a[j], a2 = a2a[j];

            float dot = a0 * v2x + a1 * v2y + a2 * v2z;
            outs[j] = pw2 * (w0a[j] * s1 * s2 + w1a[j] * is3 * dot);

            vo[3 * j + 0] = pw2 * (w2a[j] * s1 * v2x + w3a[j] * a0 * s2);
            vo[3 * j + 1] = pw2 * (w2a[j] * s1 * v2y + w3a[j] * a1 * s2);
            vo[3 * j + 2] = pw2 * (w2a[j] * s1 * v2z + w3a[j] * a2 * s2);

            float cx = a1 * v2z - a2 * v2y;
            float cy = a2 * v2x - a0 * v2z;
            float cz = a0 * v2y - a1 * v2x;
            float pww4 = pw2 * w4a[j];
            ve[3 * j + 0] = pww4 * cx;
            ve[3 * j + 1] = pww4 * cy;
            ve[3 * j + 2] = pww4 * cz;
        }
    }

    __syncthreads();   // all input reads done before aliased output writes

    // ---- write results to aliased s_out ----
    {
        float* __restrict__ po = reinterpret_cast<float*>(s_out) + r * 896;

        *reinterpret_cast<float2*>(po + c0) = make_float2(outs[0], outs[1]);

        float* vop = po + C + 3 * c0;
        *reinterpret_cast<float2*>(vop)     = make_float2(vo[0], vo[1]);
        *reinterpret_cast<float2*>(vop + 2) = make_float2(vo[2], vo[3]);
        *reinterpret_cast<float2*>(vop + 4) = make_float2(vo[4], vo[5]);

        float* vep = po + 4 * C + 3 * c0;
        *reinterpret_cast<float2*>(vep)     = make_float2(ve[0], ve[1]);
        *reinterpret_cast<float2*>(vep + 2) = make_float2(ve[2], ve[3]);
        *reinterpret_cast<float2*>(vep + 4) = make_float2(ve[4], ve[5]);
    }

    __syncthreads();

    // ---- store outputs: coalesced non-temporal dwordx4 ----
    f4v* __restrict__ gout = reinterpret_cast<f4v*>(out + n0 * 896);
    __builtin_nontemporal_store(s_out[t],       gout + t);
    __builtin_nontemporal_store(s_out[t + 256], gout + t + 256);
    __builtin_nontemporal_store(s_out[t + 512], gout + t + 512);
    if (t < 128) __builtin_nontemporal_store(s_out[t + 768], gout + t + 768);
}

extern "C" void kernel_launch(void* const* d_in, const int* in_sizes, int n_in,
                              void* d_out, int out_size, void* d_ws, size_t ws_size,
                              hipStream_t stream) {
    const float* x1 = (const float*)d_in[0];
    const float* x2 = (const float*)d_in[1];
    const float* w  = (const float*)d_in[2];
    float* out = (float*)d_out;

    int N = in_sizes[0] / (4 * C);    // 100000 (divisible by R=4)
    int grid = N / R;                 // 25000 blocks
    TensorProduct_86397562126686_kernel<<<grid, 256, 0, stream>>>(x1, x2, w, out, N);
}